// Round 1
// baseline (1305.058 us; speedup 1.0000x reference)
//
#include <hip/hip_runtime.h>
#include <stdint.h>

#define B_ 1024
#define Q_ 65536
#define D_ 512
#define MT 128
#define NT 128
#define BK 64
#define NSPLIT 64
#define NCHUNK (Q_ / NSPLIT)   // 1024
#define NTILES (NCHUNK / NT)   // 8
#define KITERS (D_ / BK)       // 8
#define LDA 72                 // padded LDS row for bf16 staging (64 + 8)
#define LDE 132                // padded LDS row for fp32 epilogue tile (16B-aligned, 33 odd)

// workspace layout (bytes):
// [0,4) ce_acc float | [4,8) neg_acc float | [8,12) npos int | [12,16) nneg int
// [16, 16+2*1024*64*8)   : LSE partials float2(M,Z), idx ((l*B+row)*64+split)
// [WS_TOPK_OFF, +2*1024*64*10*4) : top-10 partials, idx ((l*B+row)*64+split)*10
#define WS_LSE_OFF 16
#define WS_TOPK_OFF (WS_LSE_OFF + 2 * B_ * NSPLIT * 2 * 4)

typedef __attribute__((ext_vector_type(8))) short short8;
typedef __attribute__((ext_vector_type(4))) float f32x4;

__device__ __forceinline__ unsigned short f2bf(float x) {
  union { float f; uint32_t u; } v; v.f = x;
  uint32_t r = v.u + 0x7fffu + ((v.u >> 16) & 1u);   // RNE
  return (unsigned short)(r >> 16);
}

__device__ __forceinline__ void stbf4(unsigned short* dst, float4 v) {
  ushort4 u;
  u.x = f2bf(v.x); u.y = f2bf(v.y); u.z = f2bf(v.z); u.w = f2bf(v.w);
  *reinterpret_cast<ushort4*>(dst) = u;
}

// online logsumexp over one 128-col row chunk in LDS (logits = cos*32, no margin)
__device__ __forceinline__ void lse_scan_row(const float* __restrict__ rowp,
                                             float& M, float& Z) {
  const float4* r4 = reinterpret_cast<const float4*>(rowp);
  float tmax = -1e30f;
#pragma unroll
  for (int c = 0; c < NT / 4; ++c) {
    float4 v = r4[c];
    tmax = fmaxf(tmax, fmaxf(fmaxf(v.x, v.y), fmaxf(v.z, v.w)));
  }
  float Mn = fmaxf(M, tmax * 32.0f);
  float fac = __expf(M - Mn);
  float s = 0.0f;
#pragma unroll
  for (int c = 0; c < NT / 4; ++c) {
    float4 v = r4[c];
    s += __expf(fmaf(v.x, 32.0f, -Mn));
    s += __expf(fmaf(v.y, 32.0f, -Mn));
    s += __expf(fmaf(v.z, 32.0f, -Mn));
    s += __expf(fmaf(v.w, 32.0f, -Mn));
  }
  Z = fmaf(Z, fac, s);
  M = Mn;
}

// insert v into descending sorted 10-list (register resident, fully static)
__device__ __forceinline__ void tkins(float v,
    float& t0, float& t1, float& t2, float& t3, float& t4,
    float& t5, float& t6, float& t7, float& t8, float& t9) {
  if (v > t9) {
    t9 = (v > t8) ? t8 : v;
    t8 = (v > t8) ? ((v > t7) ? t7 : v) : t8;
    t7 = (v > t7) ? ((v > t6) ? t6 : v) : t7;
    t6 = (v > t6) ? ((v > t5) ? t5 : v) : t6;
    t5 = (v > t5) ? ((v > t4) ? t4 : v) : t5;
    t4 = (v > t4) ? ((v > t3) ? t3 : v) : t4;
    t3 = (v > t3) ? ((v > t2) ? t2 : v) : t3;
    t2 = (v > t2) ? ((v > t1) ? t1 : v) : t2;
    t1 = (v > t1) ? ((v > t0) ? t0 : v) : t1;
    t0 = (v > t0) ? v : t0;
  }
}

#define TK10(v, base) tkins((v), rs[(base)+0], rs[(base)+1], rs[(base)+2], rs[(base)+3], \
    rs[(base)+4], rs[(base)+5], rs[(base)+6], rs[(base)+7], rs[(base)+8], rs[(base)+9])

__global__ __launch_bounds__(256, 2) void fused_gemm_partial(
    const float* __restrict__ p, const float* __restrict__ queue,
    const float* __restrict__ maskp, const int* __restrict__ label,
    char* __restrict__ ws) {
  // epilogue tile (128 x 132 fp32) aliases the bf16 staging buffers and the
  // block-end top-k spill buffer; all uses are barrier-separated.
  __shared__ __align__(16) unsigned char smem_raw[MT * LDE * 4];  // 67584 B
  __shared__ float maskbuf[NT];
  __shared__ int olist[MT];
  __shared__ int sh_ocount;

  unsigned short* sA  = (unsigned short*)smem_raw;
  unsigned short* sB0 = sA + MT * LDA;
  unsigned short* sB1 = sB0 + NT * LDA;
  float* epi = (float*)smem_raw;
  float* tlbuf = (float*)smem_raw;

  const int tid = threadIdx.x;
  const int mblk = blockIdx.x;    // 0..7
  const int split = blockIdx.y;   // 0..63
  const int lane = tid & 63;
  const int wv = tid >> 6;
  const int wr = wv >> 1;         // wave row quadrant
  const int wc = wv & 1;          // wave col quadrant
  const int lr = lane & 15;
  const int lg = lane >> 4;

  if (tid == 0) sh_ocount = 0;
  __syncthreads();
  if (tid < MT) {
    if (label[mblk * MT + tid] == -1) {
      int k = atomicAdd(&sh_ocount, 1);
      olist[k] = tid;
    }
  }
  __syncthreads();
  const int noc = sh_ocount;
  int rowloc = -1;
  int sub = 0;
  if (tid >= 128) {
    int task = (tid - 128) >> 2;
    sub = (tid - 128) & 3;
    if (task < noc) rowloc = olist[task];
  }

  // rs[0..3]: (M1,Z1,M2,Z2) for LSE threads (tid<128)
  // rs[0..9]/rs[10..19]: top-10 lists (cos1/cos2) for topk threads (tid>=128)
  float rs[20];
#pragma unroll
  for (int i = 0; i < 20; ++i) rs[i] = -1e30f;
  if (tid < MT) { rs[1] = 0.0f; rs[3] = 0.0f; }

  for (int nt = 0; nt < NTILES; ++nt) {
    const int nbase = split * NCHUNK + nt * NT;
    if (tid >= 128) maskbuf[tid - 128] = maskp[nbase + (tid - 128)];

    f32x4 acc0[4][4], acc1[4][4];
#pragma unroll
    for (int i = 0; i < 4; ++i)
#pragma unroll
      for (int j = 0; j < 4; ++j) {
        f32x4 z = {0.0f, 0.0f, 0.0f, 0.0f};
        acc0[i][j] = z;
        acc1[i][j] = z;
      }

    for (int kk = 0; kk < KITERS; ++kk) {
      // ---- stage A, B0, B1 tiles (fp32 -> bf16) ----
#pragma unroll
      for (int j = 0; j < 8; ++j) {
        int f = j * 256 + tid;
        int r = f >> 4;
        int c4 = f & 15;
        int koff = kk * BK + c4 * 4;
        float4 va  = *(const float4*)(p + (size_t)(mblk * MT + r) * D_ + koff);
        float4 vb0 = *(const float4*)(queue + (size_t)(nbase + r) * D_ + koff);
        float4 vb1 = *(const float4*)(queue + ((size_t)Q_ + nbase + r) * D_ + koff);
        stbf4(sA  + r * LDA + c4 * 4, va);
        stbf4(sB0 + r * LDA + c4 * 4, vb0);
        stbf4(sB1 + r * LDA + c4 * 4, vb1);
      }
      __syncthreads();
      // ---- MFMA: dual accumulate (q0 and q1 share the A fragments) ----
#pragma unroll
      for (int s = 0; s < 2; ++s) {
        const int ko = s * 32 + lg * 8;
        short8 af[4], bf0[4], bf1[4];
#pragma unroll
        for (int i = 0; i < 4; ++i)
          af[i] = *(const short8*)(sA + (wr * 64 + i * 16 + lr) * LDA + ko);
#pragma unroll
        for (int j = 0; j < 4; ++j) {
          bf0[j] = *(const short8*)(sB0 + (wc * 64 + j * 16 + lr) * LDA + ko);
          bf1[j] = *(const short8*)(sB1 + (wc * 64 + j * 16 + lr) * LDA + ko);
        }
#pragma unroll
        for (int i = 0; i < 4; ++i)
#pragma unroll
          for (int j = 0; j < 4; ++j) {
            acc0[i][j] = __builtin_amdgcn_mfma_f32_16x16x32_bf16(af[i], bf0[j], acc0[i][j], 0, 0, 0);
            acc1[i][j] = __builtin_amdgcn_mfma_f32_16x16x32_bf16(af[i], bf1[j], acc1[i][j], 0, 0, 0);
          }
      }
      __syncthreads();
    }

    // ---- epilogue phase 1: cos1 = acc0 ----
#pragma unroll
    for (int i = 0; i < 4; ++i)
#pragma unroll
      for (int j = 0; j < 4; ++j)
#pragma unroll
        for (int k = 0; k < 4; ++k)
          epi[(wr * 64 + i * 16 + lg * 4 + k) * LDE + wc * 64 + j * 16 + lr] = acc0[i][j][k];
    __syncthreads();
    if (tid < MT) {
      lse_scan_row(&epi[tid * LDE], rs[0], rs[1]);
    } else if (rowloc >= 0) {
      const float4* r4 = (const float4*)(&epi[rowloc * LDE + sub * 32]);
#pragma unroll
      for (int c = 0; c < 8; ++c) {
        float4 v = r4[c];
        TK10(v.x, 0); TK10(v.y, 0); TK10(v.z, 0); TK10(v.w, 0);
      }
    }
    __syncthreads();

    // ---- epilogue phase 2: cos2 = m*G1 + (1-m)*G0 ----
    float mcol[4];
#pragma unroll
    for (int j = 0; j < 4; ++j) mcol[j] = maskbuf[wc * 64 + j * 16 + lr];
#pragma unroll
    for (int i = 0; i < 4; ++i)
#pragma unroll
      for (int j = 0; j < 4; ++j)
#pragma unroll
        for (int k = 0; k < 4; ++k) {
          float g0 = acc0[i][j][k], g1 = acc1[i][j][k];
          epi[(wr * 64 + i * 16 + lg * 4 + k) * LDE + wc * 64 + j * 16 + lr] =
              fmaf(mcol[j], g1 - g0, g0);
        }
    __syncthreads();
    if (tid < MT) {
      lse_scan_row(&epi[tid * LDE], rs[2], rs[3]);
    } else if (rowloc >= 0) {
      const float4* r4 = (const float4*)(&epi[rowloc * LDE + sub * 32]);
#pragma unroll
      for (int c = 0; c < 8; ++c) {
        float4 v = r4[c];
        TK10(v.x, 10); TK10(v.y, 10); TK10(v.z, 10); TK10(v.w, 10);
      }
    }
    __syncthreads();
  }

  // ---- block end: write LSE partials; merge 4 sub-lists per outlier row ----
  if (tid < MT) {
    int grow = mblk * MT + tid;
    float2* lseo = (float2*)(ws + WS_LSE_OFF);
    lseo[((size_t)0 * B_ + grow) * NSPLIT + split] = make_float2(rs[0], rs[1]);
    lseo[((size_t)1 * B_ + grow) * NSPLIT + split] = make_float2(rs[2], rs[3]);
  }
  if (tid >= 128) {
    float* dst = &tlbuf[(tid - 128) * 20];
#pragma unroll
    for (int i = 0; i < 20; ++i) dst[i] = rs[i];
  }
  __syncthreads();
  if (tid < 64) {
    int l = tid & 1, o = tid >> 1;
    if (o < noc) {
      float m0 = -1e30f, m1 = -1e30f, m2 = -1e30f, m3 = -1e30f, m4 = -1e30f;
      float m5 = -1e30f, m6 = -1e30f, m7 = -1e30f, m8 = -1e30f, m9 = -1e30f;
#pragma unroll
      for (int s = 0; s < 4; ++s)
#pragma unroll
        for (int i = 0; i < 10; ++i)
          tkins(tlbuf[(o * 4 + s) * 20 + l * 10 + i], m0, m1, m2, m3, m4, m5, m6, m7, m8, m9);
      int grow = mblk * MT + olist[o];
      float* dst = (float*)(ws + WS_TOPK_OFF) + ((size_t)(l * B_ + grow) * NSPLIT + (size_t)split) * 10;
      dst[0] = m0; dst[1] = m1; dst[2] = m2; dst[3] = m3; dst[4] = m4;
      dst[5] = m5; dst[6] = m6; dst[7] = m7; dst[8] = m8; dst[9] = m9;
    }
  }
}

__global__ void finalize_rows(
    const float* __restrict__ p, const float* __restrict__ queue,
    const float* __restrict__ maskp, const int* __restrict__ label,
    char* __restrict__ ws) {
  const int row = blockIdx.x;
  const int l = threadIdx.x >> 6;     // 0: loss over cos1, 1: loss over cos2
  const int lane = threadIdx.x & 63;
  const int lab = label[row];
  float* wsf = (float*)ws;
  int* wsi = (int*)ws;

  if (lab != -1) {
    // ---- merge 64 split (M,Z) partials ----
    const float2* lsep = (const float2*)(ws + WS_LSE_OFF);
    float2 mz = lsep[((size_t)l * B_ + row) * NSPLIT + lane];
    float M = mz.x;
    float Mx = M;
#pragma unroll
    for (int o = 1; o < 64; o <<= 1) Mx = fmaxf(Mx, __shfl_xor(Mx, o, 64));
    float z = mz.y * __expf(M - Mx);
#pragma unroll
    for (int o = 1; o < 64; o <<= 1) z += __shfl_xor(z, o, 64);

    // ---- exact fp32 gt dot(s) ----
    const float* prow = p + (size_t)row * D_;
    const float* q0r = queue + (size_t)lab * D_;
    const float* q1r = queue + ((size_t)Q_ + (size_t)lab) * D_;
    int c = lane * 8;
    float4 a0 = *(const float4*)(prow + c);
    float4 a1 = *(const float4*)(prow + c + 4);
    float4 b0 = *(const float4*)(q0r + c);
    float4 b1 = *(const float4*)(q0r + c + 4);
    float d0 = a0.x * b0.x + a0.y * b0.y + a0.z * b0.z + a0.w * b0.w
             + a1.x * b1.x + a1.y * b1.y + a1.z * b1.z + a1.w * b1.w;
    float d1 = 0.0f;
    if (l == 1) {
      float4 c0 = *(const float4*)(q1r + c);
      float4 c1 = *(const float4*)(q1r + c + 4);
      d1 = a0.x * c0.x + a0.y * c0.y + a0.z * c0.z + a0.w * c0.w
         + a1.x * c1.x + a1.y * c1.y + a1.z * c1.z + a1.w * c1.w;
    }
#pragma unroll
    for (int o = 1; o < 64; o <<= 1) {
      d0 += __shfl_xor(d0, o, 64);
      d1 += __shfl_xor(d1, o, 64);
    }
    float gt;
    if (l == 0) gt = d0;
    else { float m = maskp[lab]; gt = fmaf(m, d1 - d0, d0); }

    if (lane == 0) {
      // margin correction on the gt column, then ce
      float t1 = __expf(fmaf(gt, 32.0f, -Mx));
      float t2 = __expf(fmaf(gt - 0.4f, 32.0f, -Mx));
      float Zc = z - t1 + t2;
      float ce = Mx + __logf(Zc) - (gt - 0.4f) * 32.0f;
      atomicAdd(&wsf[0], ce);
      if (l == 0) atomicAdd(&wsi[2], 1);
    }
  } else {
    // ---- merge 64 sorted top-10 lists: 10-round wave tournament ----
    const float* tp = (const float*)(ws + WS_TOPK_OFF) +
                      ((size_t)(l * B_ + row) * NSPLIT + (size_t)lane) * 10;
    float t0 = tp[0], t1 = tp[1], t2 = tp[2], t3 = tp[3], t4 = tp[4];
    float t5 = tp[5], t6 = tp[6], t7 = tp[7], t8 = tp[8], t9 = tp[9];
    float ssum = 0.0f;
#pragma unroll
    for (int r10 = 0; r10 < 10; ++r10) {
      float v = t0;
      int idx = lane;
#pragma unroll
      for (int o = 1; o < 64; o <<= 1) {
        float ov = __shfl_xor(v, o, 64);
        int oi = __shfl_xor(idx, o, 64);
        bool take = (ov > v) || (ov == v && oi < idx);
        v = take ? ov : v;
        idx = take ? oi : idx;
      }
      ssum += fmaxf(v, 0.0f);
      if (idx == lane) {
        t0 = t1; t1 = t2; t2 = t3; t3 = t4; t4 = t5;
        t5 = t6; t6 = t7; t7 = t8; t8 = t9; t9 = -1e30f;
      }
    }
    if (lane == 0) {
      atomicAdd(&wsf[1], ssum * 0.1f);
      if (l == 0) atomicAdd(&wsi[3], 1);
    }
  }
}

__global__ void finalize_scalar(const char* __restrict__ ws, float* __restrict__ out) {
  const float* wsf = (const float*)ws;
  const int* wsi = (const int*)ws;
  float loss = 0.0f;
  if (wsi[2] > 0) loss += wsf[0] / (float)wsi[2];
  if (wsi[3] > 0) loss += wsf[1] / (float)wsi[3];
  out[0] = loss;
}

extern "C" void kernel_launch(void* const* d_in, const int* in_sizes, int n_in,
                              void* d_out, int out_size, void* d_ws, size_t ws_size,
                              hipStream_t stream) {
  const float* p     = (const float*)d_in[0];
  const float* queue = (const float*)d_in[1];
  const float* maskp = (const float*)d_in[2];
  const int*   label = (const int*)d_in[3];
  float* out = (float*)d_out;
  char* ws = (char*)d_ws;

  hipMemsetAsync(ws, 0, 16, stream);  // zero the atomic accumulators

  dim3 g1(B_ / MT, NSPLIT);           // (8, 64); x fastest -> blocks sharing a
                                      // queue chunk are co-resident (L2/L3 reuse)
  fused_gemm_partial<<<g1, 256, 0, stream>>>(p, queue, maskp, label, ws);
  finalize_rows<<<B_, 128, 0, stream>>>(p, queue, maskp, label, ws);
  finalize_scalar<<<1, 1, 0, stream>>>(ws, out);
}

// Round 2
// 638.913 us; speedup vs baseline: 2.0426x; 2.0426x over previous
//
#include <hip/hip_runtime.h>
#include <stdint.h>

#define B_ 1024
#define Q_ 65536
#define D_ 512
#define MT 128
#define NT 128
#define BK 64
#define NSPLIT 64
#define NCHUNK (Q_ / NSPLIT)   // 1024
#define NTILES (NCHUNK / NT)   // 8
#define KITERS (D_ / BK)       // 8

// ---- workspace layout (bytes) ----
// [0,16)    : ce_acc f32 | neg_acc f32 | npos i32 | nneg i32
// [1 KB)    : LSE partials float2(M,Z), idx ((l*B+row)*64+split)      (1 MB)
// [WS_TOPK) : top-10 partials, idx ((l*B+row)*64+split)*10            (5.24 MB)
// [8 MB)    : p in bf16   (1 MB)
// [16 MB)   : queue in bf16 (128 MB)
#define WS_ACC  0
#define WS_LSE  1024
#define WS_TOPK (WS_LSE + 2 * B_ * NSPLIT * 2 * 4)
#define WS_PBF  (8u * 1024u * 1024u)
#define WS_QBF  (16u * 1024u * 1024u)

// ---- LDS layout (aliased regions, barrier-separated) ----
// staging: sA[0,16K) sB0[16K,32K) sB1[32K,48K), each 128 rows x 128 B,
//          16B-XOR-swizzled: (r,c16) at r*128 + (c16 ^ (r&7))*16
// epilogue: epi0 bf16 [0, 33792), epi1 bf16 [33792, 67584), 264 B rows
// topk-merge spill: floats at [0, 10240)
#define SA_OFF 0
#define SB0_OFF 16384
#define SB1_OFF 32768
#define EPI_STRIDE 264
#define EPI1_OFF 33792
#define SMEM_BYTES 67584

typedef __attribute__((ext_vector_type(8))) short short8;
typedef __attribute__((ext_vector_type(4))) short short4v;
typedef __attribute__((ext_vector_type(4))) float f32x4;

__device__ __forceinline__ unsigned short f2bf(float x) {
  union { float f; uint32_t u; } v; v.f = x;
  uint32_t r = v.u + 0x7fffu + ((v.u >> 16) & 1u);   // RNE
  return (unsigned short)(r >> 16);
}

__device__ __forceinline__ float bf2f(short u) {
  union { uint32_t i; float f; } v;
  v.i = ((uint32_t)(unsigned short)u) << 16;
  return v.f;
}

// async 16B/lane global->LDS (dest = wave-uniform base + lane*16)
__device__ __forceinline__ void async16(void* lds, const void* g) {
  void* gg = (void*)g;
  __builtin_amdgcn_global_load_lds(
      (__attribute__((address_space(1))) unsigned int*)gg,
      (__attribute__((address_space(3))) unsigned int*)lds,
      16, 0, 0);
}

// two-pass online logsumexp over one 128-col bf16 row (logits = cos*32)
__device__ __forceinline__ void lse_bf_row(const unsigned char* rowp,
                                           float& M, float& Z) {
  float tmax = -1e30f;
#pragma unroll
  for (int c = 0; c < 32; ++c) {
    short4v v = *(const short4v*)(rowp + c * 8);
    tmax = fmaxf(tmax, fmaxf(fmaxf(bf2f(v.x), bf2f(v.y)),
                             fmaxf(bf2f(v.z), bf2f(v.w))));
  }
  float Mn = fmaxf(M, tmax * 32.0f);
  float fac = __expf(M - Mn);
  float s = 0.0f;
#pragma unroll
  for (int c = 0; c < 32; ++c) {
    short4v v = *(const short4v*)(rowp + c * 8);
    s += __expf(fmaf(bf2f(v.x), 32.0f, -Mn));
    s += __expf(fmaf(bf2f(v.y), 32.0f, -Mn));
    s += __expf(fmaf(bf2f(v.z), 32.0f, -Mn));
    s += __expf(fmaf(bf2f(v.w), 32.0f, -Mn));
  }
  Z = fmaf(Z, fac, s);
  M = Mn;
}

// insert v into descending sorted 10-list (register resident, fully static)
__device__ __forceinline__ void tkins(float v,
    float& t0, float& t1, float& t2, float& t3, float& t4,
    float& t5, float& t6, float& t7, float& t8, float& t9) {
  if (v > t9) {
    t9 = (v > t8) ? t8 : v;
    t8 = (v > t8) ? ((v > t7) ? t7 : v) : t8;
    t7 = (v > t7) ? ((v > t6) ? t6 : v) : t7;
    t6 = (v > t6) ? ((v > t5) ? t5 : v) : t6;
    t5 = (v > t5) ? ((v > t4) ? t4 : v) : t5;
    t4 = (v > t4) ? ((v > t3) ? t3 : v) : t4;
    t3 = (v > t3) ? ((v > t2) ? t2 : v) : t3;
    t2 = (v > t2) ? ((v > t1) ? t1 : v) : t2;
    t1 = (v > t1) ? ((v > t0) ? t0 : v) : t1;
    t0 = (v > t0) ? v : t0;
  }
}

#define TK10(v, base) tkins((v), rs[(base)+0], rs[(base)+1], rs[(base)+2], rs[(base)+3], \
    rs[(base)+4], rs[(base)+5], rs[(base)+6], rs[(base)+7], rs[(base)+8], rs[(base)+9])

// fp32 -> bf16 bulk converter (8 elems/thread/iter, 16B stores)
__global__ void cvt_bf16_kernel(const float* __restrict__ src,
                                unsigned short* __restrict__ dst, int n8) {
  int i = blockIdx.x * blockDim.x + threadIdx.x;
  int stride = gridDim.x * blockDim.x;
  for (; i < n8; i += stride) {
    const float4* s = (const float4*)src + (size_t)2 * i;
    float4 a = s[0], b = s[1];
    short8 o;
    o[0] = (short)f2bf(a.x); o[1] = (short)f2bf(a.y);
    o[2] = (short)f2bf(a.z); o[3] = (short)f2bf(a.w);
    o[4] = (short)f2bf(b.x); o[5] = (short)f2bf(b.y);
    o[6] = (short)f2bf(b.z); o[7] = (short)f2bf(b.w);
    *(short8*)(dst + (size_t)i * 8) = o;
  }
}

__global__ __launch_bounds__(256, 2) void fused_gemm_partial(
    const unsigned short* __restrict__ pbf, const unsigned short* __restrict__ qbf,
    const float* __restrict__ maskp, const int* __restrict__ label,
    char* __restrict__ ws) {
  __shared__ __align__(16) unsigned char smem[SMEM_BYTES];
  __shared__ float maskbuf[NT];
  __shared__ int olist[MT];
  __shared__ int sh_ocount;

  float* tlbuf = (float*)smem;

  const int tid = threadIdx.x;
  const int mblk = blockIdx.x;    // 0..7
  const int split = blockIdx.y;   // 0..63
  const int lane = tid & 63;
  const int wv = tid >> 6;
  const int wr = wv >> 1;         // wave row quadrant
  const int wc = wv & 1;          // wave col quadrant
  const int lr = lane & 15;
  const int lg = lane >> 4;

  if (tid == 0) sh_ocount = 0;
  __syncthreads();
  if (tid < MT) {
    if (label[mblk * MT + tid] == -1) {
      int k = atomicAdd(&sh_ocount, 1);
      olist[k] = tid;
    }
  }
  __syncthreads();
  const int noc = sh_ocount;
  int rowloc = -1;
  int sub = 0;
  if (tid >= 128) {
    int task = (tid - 128) >> 2;
    sub = (tid - 128) & 3;
    if (task < noc) rowloc = olist[task];
  }

  // per-lane staging constants: lane l covers tile row slot*8+(l>>3),
  // swizzled col16 = (l&7) ^ ((l>>3)&7)
  const int srow = lane >> 3;
  const int sc16 = (lane & 7) ^ srow;
  const size_t g_lane_off = (size_t)srow * D_ + sc16 * 8;

  // rs[0..3]: (M1,Z1,M2,Z2) for LSE threads (tid<128)
  // rs[0..9]/rs[10..19]: top-10 lists (cos1/cos2) for topk threads (tid>=128)
  float rs[20];
#pragma unroll
  for (int i = 0; i < 20; ++i) rs[i] = -1e30f;
  if (tid < MT) { rs[1] = 0.0f; rs[3] = 0.0f; }

  for (int nt = 0; nt < NTILES; ++nt) {
    const int nbase = split * NCHUNK + nt * NT;
    if (tid < NT) maskbuf[tid] = maskp[nbase + tid];

    f32x4 acc0[4][4], acc1[4][4];
#pragma unroll
    for (int i = 0; i < 4; ++i)
#pragma unroll
      for (int j = 0; j < 4; ++j) {
        f32x4 z = {0.0f, 0.0f, 0.0f, 0.0f};
        acc0[i][j] = z;
        acc1[i][j] = z;
      }

    for (int kk = 0; kk < KITERS; ++kk) {
      // ---- async stage A, B0, B1 (each tile: 16 wave-slots of 1 KB) ----
      const size_t kcol = (size_t)kk * BK;
#pragma unroll
      for (int t = 0; t < 4; ++t) {
        const int slot = wv * 4 + t;
        const size_t rbase = (size_t)slot * 8;
        async16(smem + SA_OFF + slot * 1024,
                pbf + ((size_t)mblk * MT + rbase) * D_ + kcol + g_lane_off);
        async16(smem + SB0_OFF + slot * 1024,
                qbf + ((size_t)nbase + rbase) * D_ + kcol + g_lane_off);
        async16(smem + SB1_OFF + slot * 1024,
                qbf + ((size_t)Q_ + nbase + rbase) * D_ + kcol + g_lane_off);
      }
      __syncthreads();   // drains vmcnt (global_load_lds) before barrier

      // ---- MFMA: dual accumulate (q0 and q1 share the A fragments) ----
#pragma unroll
      for (int s = 0; s < 2; ++s) {
        const int xs = ((s * 4 + lg) ^ (lr & 7)) * 16;  // swizzled 16B slot
        short8 af[4], bf0[4], bf1[4];
#pragma unroll
        for (int i = 0; i < 4; ++i)
          af[i] = *(const short8*)(smem + SA_OFF + (wr * 64 + i * 16 + lr) * 128 + xs);
#pragma unroll
        for (int j = 0; j < 4; ++j) {
          bf0[j] = *(const short8*)(smem + SB0_OFF + (wc * 64 + j * 16 + lr) * 128 + xs);
          bf1[j] = *(const short8*)(smem + SB1_OFF + (wc * 64 + j * 16 + lr) * 128 + xs);
        }
#pragma unroll
        for (int i = 0; i < 4; ++i)
#pragma unroll
          for (int j = 0; j < 4; ++j) {
            acc0[i][j] = __builtin_amdgcn_mfma_f32_16x16x32_bf16(af[i], bf0[j], acc0[i][j], 0, 0, 0);
            acc1[i][j] = __builtin_amdgcn_mfma_f32_16x16x32_bf16(af[i], bf1[j], acc1[i][j], 0, 0, 0);
          }
      }
      __syncthreads();
    }

    // ---- epilogue: write BOTH bf16 tiles (cos1, cos2) in one pass ----
    float mcol[4];
#pragma unroll
    for (int j = 0; j < 4; ++j) mcol[j] = maskbuf[wc * 64 + j * 16 + lr];
#pragma unroll
    for (int i = 0; i < 4; ++i)
#pragma unroll
      for (int j = 0; j < 4; ++j)
#pragma unroll
        for (int k = 0; k < 4; ++k) {
          const int r = wr * 64 + i * 16 + lg * 4 + k;
          const int c = wc * 64 + j * 16 + lr;
          float g0 = acc0[i][j][k], g1 = acc1[i][j][k];
          *(unsigned short*)(smem + r * EPI_STRIDE + c * 2) = f2bf(g0);
          *(unsigned short*)(smem + EPI1_OFF + r * EPI_STRIDE + c * 2) =
              f2bf(fmaf(mcol[j], g1 - g0, g0));
        }
    __syncthreads();

    // ---- scans: LSE rows (tid<128), top-10 for outlier rows (tid>=128) ----
    if (tid < MT) {
      lse_bf_row(smem + tid * EPI_STRIDE, rs[0], rs[1]);
      lse_bf_row(smem + EPI1_OFF + tid * EPI_STRIDE, rs[2], rs[3]);
    } else if (rowloc >= 0) {
      const unsigned char* b0 = smem + rowloc * EPI_STRIDE + sub * 64;
#pragma unroll
      for (int c = 0; c < 8; ++c) {
        short4v v = *(const short4v*)(b0 + c * 8);
        TK10(bf2f(v.x), 0); TK10(bf2f(v.y), 0);
        TK10(bf2f(v.z), 0); TK10(bf2f(v.w), 0);
      }
      const unsigned char* b1 = b0 + EPI1_OFF;
#pragma unroll
      for (int c = 0; c < 8; ++c) {
        short4v v = *(const short4v*)(b1 + c * 8);
        TK10(bf2f(v.x), 10); TK10(bf2f(v.y), 10);
        TK10(bf2f(v.z), 10); TK10(bf2f(v.w), 10);
      }
    }
    __syncthreads();
  }

  // ---- block end: write LSE partials; merge 4 sub-lists per outlier row ----
  if (tid < MT) {
    int grow = mblk * MT + tid;
    float2* lseo = (float2*)(ws + WS_LSE);
    lseo[((size_t)0 * B_ + grow) * NSPLIT + split] = make_float2(rs[0], rs[1]);
    lseo[((size_t)1 * B_ + grow) * NSPLIT + split] = make_float2(rs[2], rs[3]);
  }
  if (tid >= 128) {
    float* dst = &tlbuf[(tid - 128) * 20];
#pragma unroll
    for (int i = 0; i < 20; ++i) dst[i] = rs[i];
  }
  __syncthreads();
  if (tid < 64) {
    int l = tid & 1, o = tid >> 1;
    if (o < noc) {
      float m0 = -1e30f, m1 = -1e30f, m2 = -1e30f, m3 = -1e30f, m4 = -1e30f;
      float m5 = -1e30f, m6 = -1e30f, m7 = -1e30f, m8 = -1e30f, m9 = -1e30f;
#pragma unroll
      for (int s = 0; s < 4; ++s)
#pragma unroll
        for (int i = 0; i < 10; ++i)
          tkins(tlbuf[(o * 4 + s) * 20 + l * 10 + i], m0, m1, m2, m3, m4, m5, m6, m7, m8, m9);
      int grow = mblk * MT + olist[o];
      float* dst = (float*)(ws + WS_TOPK) + ((size_t)(l * B_ + grow) * NSPLIT + (size_t)split) * 10;
      dst[0] = m0; dst[1] = m1; dst[2] = m2; dst[3] = m3; dst[4] = m4;
      dst[5] = m5; dst[6] = m6; dst[7] = m7; dst[8] = m8; dst[9] = m9;
    }
  }
}

__global__ void finalize_rows(
    const float* __restrict__ p, const float* __restrict__ queue,
    const float* __restrict__ maskp, const int* __restrict__ label,
    char* __restrict__ ws) {
  const int row = blockIdx.x;
  const int l = threadIdx.x >> 6;     // 0: loss over cos1, 1: loss over cos2
  const int lane = threadIdx.x & 63;
  const int lab = label[row];
  float* wsf = (float*)ws;
  int* wsi = (int*)ws;

  if (lab != -1) {
    // ---- merge 64 split (M,Z) partials ----
    const float2* lsep = (const float2*)(ws + WS_LSE);
    float2 mz = lsep[((size_t)l * B_ + row) * NSPLIT + lane];
    float M = mz.x;
    float Mx = M;
#pragma unroll
    for (int o = 1; o < 64; o <<= 1) Mx = fmaxf(Mx, __shfl_xor(Mx, o, 64));
    float z = mz.y * __expf(M - Mx);
#pragma unroll
    for (int o = 1; o < 64; o <<= 1) z += __shfl_xor(z, o, 64);

    // ---- exact fp32 gt dot(s) ----
    const float* prow = p + (size_t)row * D_;
    const float* q0r = queue + (size_t)lab * D_;
    const float* q1r = queue + ((size_t)Q_ + (size_t)lab) * D_;
    int c = lane * 8;
    float4 a0 = *(const float4*)(prow + c);
    float4 a1 = *(const float4*)(prow + c + 4);
    float4 b0 = *(const float4*)(q0r + c);
    float4 b1 = *(const float4*)(q0r + c + 4);
    float d0 = a0.x * b0.x + a0.y * b0.y + a0.z * b0.z + a0.w * b0.w
             + a1.x * b1.x + a1.y * b1.y + a1.z * b1.z + a1.w * b1.w;
    float d1 = 0.0f;
    if (l == 1) {
      float4 c0 = *(const float4*)(q1r + c);
      float4 c1 = *(const float4*)(q1r + c + 4);
      d1 = a0.x * c0.x + a0.y * c0.y + a0.z * c0.z + a0.w * c0.w
         + a1.x * c1.x + a1.y * c1.y + a1.z * c1.z + a1.w * c1.w;
    }
#pragma unroll
    for (int o = 1; o < 64; o <<= 1) {
      d0 += __shfl_xor(d0, o, 64);
      d1 += __shfl_xor(d1, o, 64);
    }
    float gt;
    if (l == 0) gt = d0;
    else { float m = maskp[lab]; gt = fmaf(m, d1 - d0, d0); }

    if (lane == 0) {
      // margin correction on the gt column, then ce
      float t1 = __expf(fmaf(gt, 32.0f, -Mx));
      float t2 = __expf(fmaf(gt - 0.4f, 32.0f, -Mx));
      float Zc = z - t1 + t2;
      float ce = Mx + __logf(Zc) - (gt - 0.4f) * 32.0f;
      atomicAdd(&wsf[0], ce);
      if (l == 0) atomicAdd(&wsi[2], 1);
    }
  } else {
    // ---- merge 64 sorted top-10 lists: 10-round wave tournament ----
    const float* tp = (const float*)(ws + WS_TOPK) +
                      ((size_t)(l * B_ + row) * NSPLIT + (size_t)lane) * 10;
    float t0 = tp[0], t1 = tp[1], t2 = tp[2], t3 = tp[3], t4 = tp[4];
    float t5 = tp[5], t6 = tp[6], t7 = tp[7], t8 = tp[8], t9 = tp[9];
    float ssum = 0.0f;
#pragma unroll
    for (int r10 = 0; r10 < 10; ++r10) {
      float v = t0;
      int idx = lane;
#pragma unroll
      for (int o = 1; o < 64; o <<= 1) {
        float ov = __shfl_xor(v, o, 64);
        int oi = __shfl_xor(idx, o, 64);
        bool take = (ov > v) || (ov == v && oi < idx);
        v = take ? ov : v;
        idx = take ? oi : idx;
      }
      ssum += fmaxf(v, 0.0f);
      if (idx == lane) {
        t0 = t1; t1 = t2; t2 = t3; t3 = t4; t4 = t5;
        t5 = t6; t6 = t7; t7 = t8; t8 = t9; t9 = -1e30f;
      }
    }
    if (lane == 0) {
      atomicAdd(&wsf[1], ssum * 0.1f);
      if (l == 0) atomicAdd(&wsi[3], 1);
    }
  }
}

__global__ void finalize_scalar(const char* __restrict__ ws, float* __restrict__ out) {
  const float* wsf = (const float*)ws;
  const int* wsi = (const int*)ws;
  float loss = 0.0f;
  if (wsi[2] > 0) loss += wsf[0] / (float)wsi[2];
  if (wsi[3] > 0) loss += wsf[1] / (float)wsi[3];
  out[0] = loss;
}

extern "C" void kernel_launch(void* const* d_in, const int* in_sizes, int n_in,
                              void* d_out, int out_size, void* d_ws, size_t ws_size,
                              hipStream_t stream) {
  const float* p     = (const float*)d_in[0];
  const float* queue = (const float*)d_in[1];
  const float* maskp = (const float*)d_in[2];
  const int*   label = (const int*)d_in[3];
  float* out = (float*)d_out;
  char* ws = (char*)d_ws;

  unsigned short* pbf = (unsigned short*)(ws + WS_PBF);
  unsigned short* qbf = (unsigned short*)(ws + WS_QBF);

  hipMemsetAsync(ws, 0, 16, stream);  // zero the atomic accumulators

  // fp32 -> bf16 preconversion (queue: 67.1M floats, p: 0.52M floats)
  cvt_bf16_kernel<<<4096, 256, 0, stream>>>(queue, qbf, (2 * Q_ * D_) / 8);
  cvt_bf16_kernel<<<256, 256, 0, stream>>>(p, pbf, (B_ * D_) / 8);

  dim3 g1(B_ / MT, NSPLIT);           // (8, 64); x fastest -> blocks sharing a
                                      // queue chunk spread across XCDs, L3-resident
  fused_gemm_partial<<<g1, 256, 0, stream>>>(pbf, qbf, maskp, label, ws);
  finalize_rows<<<B_, 128, 0, stream>>>(p, queue, maskp, label, ws);
  finalize_scalar<<<1, 1, 0, stream>>>(ws, out);
}